// Round 5
// baseline (410.400 us; speedup 1.0000x reference)
//
#include <hip/hip_runtime.h>

// ---------------------------------------------------------------------------
// Types
// ---------------------------------------------------------------------------
typedef __bf16 bf16x8 __attribute__((ext_vector_type(8)));
typedef float f32x4 __attribute__((ext_vector_type(4)));
typedef unsigned short ushort_t;

#define THREADS 256

__device__ __forceinline__ unsigned short f2bf(float f) {
  unsigned int u = __builtin_bit_cast(unsigned int, f);
  u += 0x7fffu + ((u >> 16) & 1u);   // RNE (no NaN in this data)
  return (unsigned short)(u >> 16);
}

__device__ __forceinline__ float bf2f(ushort_t u) {
  unsigned int v = ((unsigned int)u) << 16;
  return __builtin_bit_cast(float, v);
}

__device__ __forceinline__ void gload_lds16(const ushort_t* g, ushort_t* l) {
  __builtin_amdgcn_global_load_lds(
      (const __attribute__((address_space(1))) void*)g,
      (__attribute__((address_space(3))) void*)l, 16, 0, 0);
}

// ---------------------------------------------------------------------------
// Cast / transpose kernels
// ---------------------------------------------------------------------------
__global__ void cast_x_kernel(const float4* __restrict__ src,
                              ushort4* __restrict__ dst, int n4) {
  int stride = gridDim.x * blockDim.x;
  for (int i = blockIdx.x * blockDim.x + threadIdx.x; i < n4; i += stride) {
    float4 v = src[i];
    ushort4 o;
    o.x = f2bf(v.x); o.y = f2bf(v.y); o.z = f2bf(v.z); o.w = f2bf(v.w);
    dst[i] = o;
  }
}

// dst[z][c][r] = (bf16) src[z][r][c];   block (32,8), grid (C/32, R/32, Z)
__global__ void transpose_cast_kernel(const float* __restrict__ src,
                                      ushort_t* __restrict__ dst, int R, int C) {
  __shared__ float t[32][33];
  size_t zoff = (size_t)blockIdx.z * R * C;
  src += zoff; dst += zoff;
  int c0 = blockIdx.x * 32, r0 = blockIdx.y * 32;
  int tx = threadIdx.x, ty = threadIdx.y;
#pragma unroll
  for (int i = 0; i < 4; ++i)
    t[ty + 8 * i][tx] = src[(size_t)(r0 + ty + 8 * i) * C + c0 + tx];
  __syncthreads();
#pragma unroll
  for (int i = 0; i < 4; ++i)
    dst[(size_t)(c0 + ty + 8 * i) * R + r0 + tx] = f2bf(t[tx][ty + 8 * i]);
}

// ---------------------------------------------------------------------------
// Swizzled staging (proven conflict-free).
// LDS tile [ROWS][32] bf16; slot s of row holds global k-chunk s ^ ((row>>1)&3).
// ---------------------------------------------------------------------------
__device__ __forceinline__ int sw(int row) { return (row >> 1) & 3; }

__device__ __forceinline__ bf16x8 frag_sw(const ushort_t* lds, int row, int q) {
  int slot = q ^ sw(row);
  return *(const bf16x8*)(lds + (row * 4 + slot) * 8);
}

#define ACC_ZERO(acc, MM, NN)                        \
  _Pragma("unroll") for (int _i = 0; _i < MM; ++_i)  \
  _Pragma("unroll") for (int _j = 0; _j < NN; ++_j)  \
      acc[_i][_j] = (f32x4){0.f, 0.f, 0.f, 0.f};

// ---------------------------------------------------------------------------
// Lean 2-phase GEMM with double-buffered prefetch (T3-minimum):
//   prologue: STAGE(t=0); barrier
//   iter t:   STAGE(t+1 -> other buf); ds_read+MFMA(cur buf); barrier
// One barrier per K-step; STAGE(t+1) overlaps with compute(t).
// Tile BM x BN, acc[4][4]/wave, BK=32, 256 threads, ~90 VGPR.
// ---------------------------------------------------------------------------
template <int BM, int BN>
__device__ __forceinline__ void stage_tiles(const ushort_t* __restrict__ A,
                                            size_t lda, int arow0,
                                            const ushort_t* __restrict__ BT,
                                            size_t ldb, int brow0, int k0,
                                            ushort_t* As, ushort_t* Bs,
                                            int tid) {
#pragma unroll
  for (int i = 0; i < BM / 64; ++i) {
    int c = tid + i * THREADS;
    int row = c >> 2, slot = c & 3;
    int g = slot ^ sw(row);
    gload_lds16(A + (size_t)(arow0 + row) * lda + k0 + g * 8, As + c * 8);
  }
#pragma unroll
  for (int i = 0; i < BN / 64; ++i) {
    int c = tid + i * THREADS;
    int row = c >> 2, slot = c & 3;
    int g = slot ^ sw(row);
    gload_lds16(BT + (size_t)(brow0 + row) * ldb + k0 + g * 8, Bs + c * 8);
  }
}

__device__ __forceinline__ void mma_step(const ushort_t* As, const ushort_t* Bs,
                                         int wm, int wn, int lane,
                                         f32x4 acc[4][4]) {
  int r = lane & 15, q = lane >> 4;
  bf16x8 a[4], b[4];
#pragma unroll
  for (int mi = 0; mi < 4; ++mi)
    a[mi] = frag_sw(As, wm * 64 + mi * 16 + r, q);
#pragma unroll
  for (int ni = 0; ni < 4; ++ni)
    b[ni] = frag_sw(Bs, wn * 64 + ni * 16 + r, q);
#pragma unroll
  for (int mi = 0; mi < 4; ++mi)
#pragma unroll
    for (int ni = 0; ni < 4; ++ni)
      acc[mi][ni] =
          __builtin_amdgcn_mfma_f32_16x16x32_bf16(a[mi], b[ni], acc[mi][ni], 0, 0, 0);
}

// As: [2][BM*32] ushorts, Bs: [2][BN*32] ushorts
template <int BM, int BN>
__device__ __forceinline__ void gemm_kloop(const ushort_t* __restrict__ A,
                                           size_t lda, int arow0,
                                           const ushort_t* __restrict__ BT,
                                           size_t ldb, int brow0, int K,
                                           ushort_t* As, ushort_t* Bs, int tid,
                                           int wm, int wn, f32x4 acc[4][4]) {
  int lane = tid & 63;
  int nt = K >> 5;
  stage_tiles<BM, BN>(A, lda, arow0, BT, ldb, brow0, 0, As, Bs, tid);
  __syncthreads();
  for (int t = 0; t < nt; ++t) {
    int cur = t & 1, nxt = cur ^ 1;
    if (t + 1 < nt)
      stage_tiles<BM, BN>(A, lda, arow0, BT, ldb, brow0, (t + 1) * 32,
                          As + nxt * (BM * 32), Bs + nxt * (BN * 32), tid);
    mma_step(As + cur * (BM * 32), Bs + cur * (BN * 32), wm, wn, lane, acc);
    __syncthreads();
  }
}

#define ACC_INIT(acc)  \
  f32x4 acc[4][4];     \
  ACC_ZERO(acc, 4, 4)

// ---------------------------------------------------------------------------
// disc_h: h = relu(x @ Wd1_all + bd1_all), one GEMM M=16384, N=2048, K=1024.
// Output scattered into h[e][16384][256] layout (e = col>>8).
// 1D grid 2048, XCD-chunked.
// ---------------------------------------------------------------------------
__global__ __launch_bounds__(THREADS) void disc_h_kernel(
    const ushort_t* __restrict__ x_bf, const ushort_t* __restrict__ Wd1T,
    const float* __restrict__ bd1, ushort_t* __restrict__ h) {
  __shared__ ushort_t As[2 * 128 * 32], Bs[2 * 128 * 32];
  int b = blockIdx.x;
  int work = (b & 7) * 256 + (b >> 3);   // bijective XCD chunk (2048 % 8 == 0)
  int m0 = (work >> 4) * 128;            // 16 consecutive m-tiles per XCD
  int n0 = (work & 15) * 128;
  int tid = threadIdx.x, wid = tid >> 6, lane = tid & 63;
  int wm = wid >> 1, wn = wid & 1;
  ACC_INIT(acc);
  gemm_kloop<128, 128>(x_bf, 1024, m0, Wd1T, 1024, n0, 1024, As, Bs, tid, wm,
                       wn, acc);
  int r = lane & 15, q = lane >> 4;
#pragma unroll
  for (int ni = 0; ni < 4; ++ni) {
    int col = n0 + wn * 64 + ni * 16 + r;
    float bias = bd1[col];
    int e = col >> 8, nn = col & 255;
    ushort_t* hp = h + (size_t)e * 16384 * 256 + nn;
#pragma unroll
    for (int mi = 0; mi < 4; ++mi) {
      int rowb = m0 + wm * 64 + mi * 16 + q * 4;
#pragma unroll
      for (int j = 0; j < 4; ++j) {
        float v = fmaxf(acc[mi][ni][j] + bias, 0.f);
        hp[(size_t)(rowb + j) * 256] = f2bf(v);
      }
    }
  }
}

// ---------------------------------------------------------------------------
// disc_loss: recon = h[e] @ Wd2[e] + bd2[e]; sum((recon - x)^2) -> losses.
// Tile 128x128, K=256.  1D grid 8192; expert e -> XCD e.
// ---------------------------------------------------------------------------
__global__ __launch_bounds__(THREADS) void disc_loss_kernel(
    const ushort_t* __restrict__ h, const ushort_t* __restrict__ Wd2T,
    const float* __restrict__ bd2, const ushort_t* __restrict__ x_bf,
    float* __restrict__ losses) {
  __shared__ ushort_t As[2 * 128 * 32], Bs[2 * 128 * 32];
  __shared__ float red[4];
  int b = blockIdx.x;
  int work = (b & 7) * 1024 + (b >> 3);  // 8192 % 8 == 0
  int e = work >> 10;                    // 1024 blocks per expert -> one XCD
  int m0 = ((work >> 3) & 127) * 128;
  int n0 = (work & 7) * 128;
  int tid = threadIdx.x, wid = tid >> 6, lane = tid & 63;
  int wm = wid >> 1, wn = wid & 1;
  int r = lane & 15, q = lane >> 4;
  const ushort_t* hA = h + (size_t)e * 16384 * 256;
  const ushort_t* W2 = Wd2T + (size_t)e * 1024 * 256;

  ACC_INIT(acc);
  gemm_kloop<128, 128>(hA, 256, m0, W2, 256, n0, 256, As, Bs, tid, wm, wn, acc);

  float s = 0.f;
#pragma unroll
  for (int ni = 0; ni < 4; ++ni) {
    int colg = n0 + wn * 64 + ni * 16 + r;
    float bias = bd2[e * 1024 + colg];
#pragma unroll
    for (int mi = 0; mi < 4; ++mi) {
      int rowg = m0 + wm * 64 + mi * 16 + q * 4;
#pragma unroll
      for (int j = 0; j < 4; ++j) {
        float v = acc[mi][ni][j] + bias -
                  bf2f(x_bf[(size_t)(rowg + j) * 1024 + colg]);
        s += v * v;
      }
    }
  }
#pragma unroll
  for (int off = 32; off > 0; off >>= 1) s += __shfl_down(s, off);
  if (lane == 0) red[wid] = s;
  __syncthreads();
  if (tid == 0) {
    float t = red[0] + red[1] + red[2] + red[3];
    atomicAdd(&losses[e * 8 + (m0 >> 11)], t);
  }
}

__global__ void zero_losses_kernel(float* __restrict__ losses) {
  losses[threadIdx.x] = 0.f;
}

__global__ void argmin_kernel(const float* __restrict__ losses,
                              int* __restrict__ idx) {
  int b = threadIdx.x;
  if (b < 8) {
    float best = losses[b];
    int bi = 0;
    for (int e = 1; e < 8; ++e) {
      float v = losses[e * 8 + b];
      if (v < best) { best = v; bi = e; }
    }
    idx[b] = bi;
  }
}

// ---------------------------------------------------------------------------
// Adapter down: a = relu(x @ Wa_down[idx[b]] + ba_down[idx[b]]), bf16 out.
// ---------------------------------------------------------------------------
__global__ __launch_bounds__(THREADS) void adapter_down_kernel(
    const ushort_t* __restrict__ x, const ushort_t* __restrict__ WadT,
    const float* __restrict__ ba_down, const int* __restrict__ idx,
    ushort_t* __restrict__ a) {
  __shared__ ushort_t As[2 * 256 * 32], Bs[2 * 64 * 32];
  int m0 = blockIdx.x * 256;
  int e = idx[m0 >> 11];
  int tid = threadIdx.x, wid = tid >> 6, lane = tid & 63;
  ACC_INIT(acc);
  gemm_kloop<256, 64>(x, 1024, m0, WadT + (size_t)e * 64 * 1024, 1024, 0, 1024,
                      As, Bs, tid, wid, 0, acc);
  int r = lane & 15, q = lane >> 4;
#pragma unroll
  for (int ni = 0; ni < 4; ++ni) {
    int col = ni * 16 + r;
    float bias = ba_down[e * 64 + col];
#pragma unroll
    for (int mi = 0; mi < 4; ++mi) {
      int rowb = m0 + wid * 64 + mi * 16 + q * 4;
#pragma unroll
      for (int j = 0; j < 4; ++j) {
        float v = acc[mi][ni][j] + bias;
        v = fmaxf(v, 0.f);
        a[(size_t)(rowb + j) * 64 + col] = f2bf(v);
      }
    }
  }
}

// ---------------------------------------------------------------------------
// Final: out = x @ W_base + b_base + a @ Wa_up[idx[b]] + ba_up[idx[b]]
// 1D grid 1024, XCD-chunked.
// ---------------------------------------------------------------------------
__global__ __launch_bounds__(THREADS) void final_kernel(
    const ushort_t* __restrict__ x, const ushort_t* __restrict__ WbT,
    const float* __restrict__ b_base, const ushort_t* __restrict__ a,
    const ushort_t* __restrict__ WauT, const float* __restrict__ ba_up,
    const int* __restrict__ idx, float* __restrict__ out) {
  __shared__ ushort_t As[2 * 128 * 32], Bs[2 * 128 * 32];
  int b = blockIdx.x;
  int work = (b & 7) * 128 + (b >> 3);   // 1024 % 8 == 0
  int m0 = (work >> 3) * 128;
  int n0 = (work & 7) * 128;
  int e = idx[m0 >> 11];
  int tid = threadIdx.x, wid = tid >> 6, lane = tid & 63;
  int wm = wid >> 1, wn = wid & 1;
  ACC_INIT(acc);
  gemm_kloop<128, 128>(x, 1024, m0, WbT, 1024, n0, 1024, As, Bs, tid, wm, wn, acc);
  gemm_kloop<128, 128>(a, 64, m0, WauT + (size_t)e * 1024 * 64, 64, n0, 64, As,
                       Bs, tid, wm, wn, acc);
  int r = lane & 15, q = lane >> 4;
#pragma unroll
  for (int ni = 0; ni < 4; ++ni) {
    int col = n0 + wn * 64 + ni * 16 + r;
    float bias = b_base[col] + ba_up[e * 1024 + col];
#pragma unroll
    for (int mi = 0; mi < 4; ++mi) {
      int rowb = m0 + wm * 64 + mi * 16 + q * 4;
#pragma unroll
      for (int j = 0; j < 4; ++j)
        out[(size_t)(rowb + j) * 1024 + col] = acc[mi][ni][j] + bias;
    }
  }
}

// ---------------------------------------------------------------------------
// Host launcher
// ---------------------------------------------------------------------------
extern "C" void kernel_launch(void* const* d_in, const int* in_sizes, int n_in,
                              void* d_out, int out_size, void* d_ws,
                              size_t ws_size, hipStream_t stream) {
  const float* x       = (const float*)d_in[0];
  const float* W_base  = (const float*)d_in[1];
  const float* b_base  = (const float*)d_in[2];
  const float* Wd1     = (const float*)d_in[3];
  const float* bd1     = (const float*)d_in[4];
  const float* Wd2     = (const float*)d_in[5];
  const float* bd2     = (const float*)d_in[6];
  const float* Wa_down = (const float*)d_in[7];
  const float* ba_down = (const float*)d_in[8];
  const float* Wa_up   = (const float*)d_in[9];
  const float* ba_up   = (const float*)d_in[10];
  float* out = (float*)d_out;

  char* w = (char*)d_ws;
  size_t off = 0;
  auto alloc = [&](size_t bytes) {
    void* p = w + off;
    off += (bytes + 255) & ~(size_t)255;
    return p;
  };
  ushort_t* x_bf = (ushort_t*)alloc((size_t)16384 * 1024 * 2);
  ushort_t* Wd1T = (ushort_t*)alloc((size_t)8 * 256 * 1024 * 2);
  ushort_t* Wd2T = (ushort_t*)alloc((size_t)8 * 1024 * 256 * 2);
  ushort_t* WbT  = (ushort_t*)alloc((size_t)1024 * 1024 * 2);
  ushort_t* WadT = (ushort_t*)alloc((size_t)8 * 64 * 1024 * 2);
  ushort_t* WauT = (ushort_t*)alloc((size_t)8 * 1024 * 64 * 2);
  ushort_t* abuf = (ushort_t*)alloc((size_t)16384 * 64 * 2);
  float* losses  = (float*)alloc(64 * 4);
  int* idxb      = (int*)alloc(64);
  size_t hbytes = (size_t)8 * 16384 * 256 * 2;  // 67 MB
  ushort_t* h = (ws_size >= off + hbytes) ? (ushort_t*)alloc(hbytes)
                                          : (ushort_t*)d_out;  // out rewritten later

  // casts + transposes
  cast_x_kernel<<<2048, 256, 0, stream>>>((const float4*)x, (ushort4*)x_bf,
                                          16777216 / 4);
  transpose_cast_kernel<<<dim3(256 / 32, 1024 / 32, 8), dim3(32, 8), 0, stream>>>(
      Wd1, Wd1T, 1024, 256);
  transpose_cast_kernel<<<dim3(1024 / 32, 256 / 32, 8), dim3(32, 8), 0, stream>>>(
      Wd2, Wd2T, 256, 1024);
  transpose_cast_kernel<<<dim3(32, 32, 1), dim3(32, 8), 0, stream>>>(
      W_base, WbT, 1024, 1024);
  transpose_cast_kernel<<<dim3(2, 32, 8), dim3(32, 8), 0, stream>>>(
      Wa_down, WadT, 1024, 64);
  transpose_cast_kernel<<<dim3(32, 2, 8), dim3(32, 8), 0, stream>>>(
      Wa_up, WauT, 64, 1024);
  zero_losses_kernel<<<1, 64, 0, stream>>>(losses);

  // discriminators
  disc_h_kernel<<<2048, THREADS, 0, stream>>>(x_bf, Wd1T, bd1, h);
  disc_loss_kernel<<<8192, THREADS, 0, stream>>>(h, Wd2T, bd2, x_bf, losses);
  argmin_kernel<<<1, 64, 0, stream>>>(losses, idxb);

  // adapter + base
  adapter_down_kernel<<<64, THREADS, 0, stream>>>(x_bf, WadT, ba_down, idxb,
                                                  abuf);
  final_kernel<<<1024, THREADS, 0, stream>>>(x_bf, WbT, b_base, abuf,
                                             WauT, ba_up, idxb, out);
}

// Round 6
// 380.854 us; speedup vs baseline: 1.0776x; 1.0776x over previous
//
#include <hip/hip_runtime.h>

// ---------------------------------------------------------------------------
// Types
// ---------------------------------------------------------------------------
typedef __bf16 bf16x8 __attribute__((ext_vector_type(8)));
typedef float f32x4 __attribute__((ext_vector_type(4)));
typedef unsigned short ushort_t;

#define THREADS 256

__device__ __forceinline__ unsigned short f2bf(float f) {
  unsigned int u = __builtin_bit_cast(unsigned int, f);
  u += 0x7fffu + ((u >> 16) & 1u);   // RNE (no NaN in this data)
  return (unsigned short)(u >> 16);
}

__device__ __forceinline__ float bf2f(ushort_t u) {
  unsigned int v = ((unsigned int)u) << 16;
  return __builtin_bit_cast(float, v);
}

__device__ __forceinline__ void gload_lds16(const ushort_t* g, ushort_t* l) {
  __builtin_amdgcn_global_load_lds(
      (const __attribute__((address_space(1))) void*)g,
      (__attribute__((address_space(3))) void*)l, 16, 0, 0);
}

// ---------------------------------------------------------------------------
// cast x -> bf16 (also zeros nothing; losses zeroed in transpose_all)
// ---------------------------------------------------------------------------
__global__ void cast_x_kernel(const float4* __restrict__ src,
                              ushort4* __restrict__ dst, int n4) {
  int stride = gridDim.x * blockDim.x;
  for (int i = blockIdx.x * blockDim.x + threadIdx.x; i < n4; i += stride) {
    float4 v = src[i];
    ushort4 o;
    o.x = f2bf(v.x); o.y = f2bf(v.y); o.z = f2bf(v.z); o.w = f2bf(v.w);
    dst[i] = o;
  }
}

// ---------------------------------------------------------------------------
// All weight transposes in ONE kernel.  block (32,8); 6144 blocks total.
//   [0,2048)   Wd1  [8][1024][256]  -> Wd1T [8][256][1024]
//   [2048,4096) Wd2 [8][256][1024]  -> Wd2T [8][1024][256]
//   [4096,5120) Wb  [1024][1024]    -> WbT  [1024][1024]
//   [5120,5632) Wad [8][1024][64]   -> WadT [8][64][1024]
//   [5632,6144) Wau [8][64][1024]   -> WauT [8][1024][64]
// Also zeroes losses[64] (block 0).
// ---------------------------------------------------------------------------
__global__ void transpose_all_kernel(
    const float* __restrict__ Wd1, const float* __restrict__ Wd2,
    const float* __restrict__ Wb, const float* __restrict__ Wad,
    const float* __restrict__ Wau, ushort_t* __restrict__ Wd1T,
    ushort_t* __restrict__ Wd2T, ushort_t* __restrict__ WbT,
    ushort_t* __restrict__ WadT, ushort_t* __restrict__ WauT,
    float* __restrict__ losses) {
  __shared__ float t[32][33];
  int b = blockIdx.x;
  int tx = threadIdx.x, ty = threadIdx.y;
  int ft = ty * 32 + tx;
  if (b == 0 && ft < 64) losses[ft] = 0.f;

  const float* src;
  ushort_t* dst;
  int R, C, z, cx, ry;
  if (b < 2048) {
    src = Wd1; dst = Wd1T; R = 1024; C = 256;
    z = b >> 8; int rem = b & 255; cx = rem & 7; ry = rem >> 3;
  } else if (b < 4096) {
    int bb = b - 2048;
    src = Wd2; dst = Wd2T; R = 256; C = 1024;
    z = bb >> 8; int rem = bb & 255; cx = rem & 31; ry = rem >> 5;
  } else if (b < 5120) {
    int bb = b - 4096;
    src = Wb; dst = WbT; R = 1024; C = 1024;
    z = 0; cx = bb & 31; ry = bb >> 5;
  } else if (b < 5632) {
    int bb = b - 5120;
    src = Wad; dst = WadT; R = 1024; C = 64;
    z = bb >> 6; int rem = bb & 63; cx = rem & 1; ry = rem >> 1;
  } else {
    int bb = b - 5632;
    src = Wau; dst = WauT; R = 64; C = 1024;
    z = bb >> 6; int rem = bb & 63; cx = rem & 31; ry = rem >> 5;
  }
  size_t zoff = (size_t)z * R * C;
  src += zoff; dst += zoff;
  int c0 = cx * 32, r0 = ry * 32;
#pragma unroll
  for (int i = 0; i < 4; ++i)
    t[ty + 8 * i][tx] = src[(size_t)(r0 + ty + 8 * i) * C + c0 + tx];
  __syncthreads();
#pragma unroll
  for (int i = 0; i < 4; ++i)
    dst[(size_t)(c0 + ty + 8 * i) * R + r0 + tx] = f2bf(t[tx][ty + 8 * i]);
}

// ---------------------------------------------------------------------------
// BK=64 swizzled staging.  LDS tile [ROWS][64] bf16 = 8 chunks of 16B/row.
// Involution: LDS slot s of row holds global k-chunk s ^ (row&7).
// Read (row, chunk c) -> slot c ^ (row&7).  16 lanes x rows 0..15 at fixed c
// -> 8 distinct 16B slots -> 2-way aliasing (free, m136).
// ---------------------------------------------------------------------------
template <int ROWS>
__device__ __forceinline__ void stage64(const ushort_t* __restrict__ src,
                                        size_t ld, int row0, int k0,
                                        ushort_t* lds, int tid) {
#pragma unroll
  for (int i = 0; i < ROWS * 8 / THREADS; ++i) {
    int c = tid + i * THREADS;
    int row = c >> 3, slot = c & 7;
    int g = slot ^ (row & 7);
    gload_lds16(src + (size_t)(row0 + row) * ld + k0 + g * 8, lds + c * 8);
  }
}

__device__ __forceinline__ bf16x8 frag_sw8(const ushort_t* lds, int row, int c) {
  int slot = c ^ (row & 7);
  return *(const bf16x8*)(lds + row * 64 + slot * 8);
}

#define ACC_ZERO(acc, MM, NN)                        \
  _Pragma("unroll") for (int _i = 0; _i < MM; ++_i)  \
  _Pragma("unroll") for (int _j = 0; _j < NN; ++_j)  \
      acc[_i][_j] = (f32x4){0.f, 0.f, 0.f, 0.f};

// one BK=64 step: two k-halves, each {8 ds_read_b128, 16 MFMA}
__device__ __forceinline__ void mma_step64(const ushort_t* As,
                                           const ushort_t* Bs, int wm, int wn,
                                           int lane, f32x4 acc[4][4]) {
  int r = lane & 15, q = lane >> 4;
#pragma unroll
  for (int h = 0; h < 2; ++h) {
    int c = h * 4 + q;   // global k-chunk; frag k = c*8+j = h*32 + q*8 + j
    bf16x8 a[4], b[4];
#pragma unroll
    for (int mi = 0; mi < 4; ++mi)
      a[mi] = frag_sw8(As, wm * 64 + mi * 16 + r, c);
#pragma unroll
    for (int ni = 0; ni < 4; ++ni)
      b[ni] = frag_sw8(Bs, wn * 64 + ni * 16 + r, c);
#pragma unroll
    for (int mi = 0; mi < 4; ++mi)
#pragma unroll
      for (int ni = 0; ni < 4; ++ni)
        acc[mi][ni] = __builtin_amdgcn_mfma_f32_16x16x32_bf16(
            a[mi], b[ni], acc[mi][ni], 0, 0, 0);
  }
}

// Proven round-4 sync structure: stage -> sync -> mma -> sync, BK=64.
template <int BM, int BN>
__device__ __forceinline__ void gemm_kloop64(const ushort_t* __restrict__ A,
                                             size_t lda, int arow0,
                                             const ushort_t* __restrict__ BT,
                                             size_t ldb, int brow0, int K,
                                             ushort_t* As, ushort_t* Bs,
                                             int tid, int wm, int wn,
                                             f32x4 acc[4][4]) {
  int lane = tid & 63;
  for (int k0 = 0; k0 < K; k0 += 64) {
    stage64<BM>(A, lda, arow0, k0, As, tid);
    stage64<BN>(BT, ldb, brow0, k0, Bs, tid);
    __syncthreads();
    mma_step64(As, Bs, wm, wn, lane, acc);
    __syncthreads();
  }
}

#define ACC_INIT(acc)  \
  f32x4 acc[4][4];     \
  ACC_ZERO(acc, 4, 4)

// ---------------------------------------------------------------------------
// disc_h: h = relu(x @ Wd1_all + bd1_all), one GEMM M=16384, N=2048, K=1024.
// Output scattered into h[e][16384][256] (e = col>>8).  1D grid 2048,
// XCD-chunked (16 consecutive m-tiles per XCD, n fastest).
// ---------------------------------------------------------------------------
__global__ __launch_bounds__(THREADS) void disc_h_kernel(
    const ushort_t* __restrict__ x_bf, const ushort_t* __restrict__ Wd1T,
    const float* __restrict__ bd1, ushort_t* __restrict__ h) {
  __shared__ ushort_t As[128 * 64], Bs[128 * 64];
  int b = blockIdx.x;
  int work = (b & 7) * 256 + (b >> 3);   // bijective (2048 % 8 == 0)
  int m0 = (work >> 4) * 128;
  int n0 = (work & 15) * 128;
  int tid = threadIdx.x, wid = tid >> 6, lane = tid & 63;
  int wm = wid >> 1, wn = wid & 1;
  ACC_INIT(acc);
  gemm_kloop64<128, 128>(x_bf, 1024, m0, Wd1T, 1024, n0, 1024, As, Bs, tid,
                         wm, wn, acc);
  int r = lane & 15, q = lane >> 4;
#pragma unroll
  for (int ni = 0; ni < 4; ++ni) {
    int col = n0 + wn * 64 + ni * 16 + r;
    float bias = bd1[col];
    int e = col >> 8, nn = col & 255;
    ushort_t* hp = h + (size_t)e * 16384 * 256 + nn;
#pragma unroll
    for (int mi = 0; mi < 4; ++mi) {
      int rowb = m0 + wm * 64 + mi * 16 + q * 4;
#pragma unroll
      for (int j = 0; j < 4; ++j) {
        float v = fmaxf(acc[mi][ni][j] + bias, 0.f);
        hp[(size_t)(rowb + j) * 256] = f2bf(v);
      }
    }
  }
}

// ---------------------------------------------------------------------------
// disc_loss: recon = h[e] @ Wd2[e] + bd2[e]; sum((recon-x)^2) -> losses.
// Tile 128x128, K=256 (4 BK=64 steps).  1D grid 8192; expert e -> XCD e.
// ---------------------------------------------------------------------------
__global__ __launch_bounds__(THREADS) void disc_loss_kernel(
    const ushort_t* __restrict__ h, const ushort_t* __restrict__ Wd2T,
    const float* __restrict__ bd2, const ushort_t* __restrict__ x_bf,
    float* __restrict__ losses) {
  __shared__ ushort_t As[128 * 64], Bs[128 * 64];
  __shared__ float red[4];
  int b = blockIdx.x;
  int work = (b & 7) * 1024 + (b >> 3);  // 8192 % 8 == 0
  int e = work >> 10;                    // 1024 blocks per expert -> one XCD
  int m0 = ((work >> 3) & 127) * 128;
  int n0 = (work & 7) * 128;
  int tid = threadIdx.x, wid = tid >> 6, lane = tid & 63;
  int wm = wid >> 1, wn = wid & 1;
  int r = lane & 15, q = lane >> 4;
  const ushort_t* hA = h + (size_t)e * 16384 * 256;
  const ushort_t* W2 = Wd2T + (size_t)e * 1024 * 256;

  ACC_INIT(acc);
  gemm_kloop64<128, 128>(hA, 256, m0, W2, 256, n0, 256, As, Bs, tid, wm, wn,
                         acc);

  float s = 0.f;
#pragma unroll
  for (int ni = 0; ni < 4; ++ni) {
    int colg = n0 + wn * 64 + ni * 16 + r;
    float bias = bd2[e * 1024 + colg];
#pragma unroll
    for (int mi = 0; mi < 4; ++mi) {
      int rowg = m0 + wm * 64 + mi * 16 + q * 4;
#pragma unroll
      for (int j = 0; j < 4; ++j) {
        float v = acc[mi][ni][j] + bias -
                  bf2f(x_bf[(size_t)(rowg + j) * 1024 + colg]);
        s += v * v;
      }
    }
  }
#pragma unroll
  for (int off = 32; off > 0; off >>= 1) s += __shfl_down(s, off);
  if (lane == 0) red[wid] = s;
  __syncthreads();
  if (tid == 0) {
    float t = red[0] + red[1] + red[2] + red[3];
    atomicAdd(&losses[e * 8 + (m0 >> 11)], t);
  }
}

__global__ void argmin_kernel(const float* __restrict__ losses,
                              int* __restrict__ idx) {
  int b = threadIdx.x;
  if (b < 8) {
    float best = losses[b];
    int bi = 0;
    for (int e = 1; e < 8; ++e) {
      float v = losses[e * 8 + b];
      if (v < best) { best = v; bi = e; }
    }
    idx[b] = bi;
  }
}

// ---------------------------------------------------------------------------
// Adapter down: a = relu(x @ Wa_down[idx[b]] + ba_down[idx[b]]), bf16 out.
// Tile 256x64, K=1024 (16 steps).  grid 64.
// ---------------------------------------------------------------------------
__global__ __launch_bounds__(THREADS) void adapter_down_kernel(
    const ushort_t* __restrict__ x, const ushort_t* __restrict__ WadT,
    const float* __restrict__ ba_down, const int* __restrict__ idx,
    ushort_t* __restrict__ a) {
  __shared__ ushort_t As[256 * 64], Bs[64 * 64];
  int m0 = blockIdx.x * 256;
  int e = idx[m0 >> 11];
  int tid = threadIdx.x, wid = tid >> 6, lane = tid & 63;
  ACC_INIT(acc);
  gemm_kloop64<256, 64>(x, 1024, m0, WadT + (size_t)e * 64 * 1024, 1024, 0,
                        1024, As, Bs, tid, wid, 0, acc);
  int r = lane & 15, q = lane >> 4;
#pragma unroll
  for (int ni = 0; ni < 4; ++ni) {
    int col = ni * 16 + r;
    float bias = ba_down[e * 64 + col];
#pragma unroll
    for (int mi = 0; mi < 4; ++mi) {
      int rowb = m0 + wid * 64 + mi * 16 + q * 4;
#pragma unroll
      for (int j = 0; j < 4; ++j) {
        float v = acc[mi][ni][j] + bias;
        v = fmaxf(v, 0.f);
        a[(size_t)(rowb + j) * 64 + col] = f2bf(v);
      }
    }
  }
}

// ---------------------------------------------------------------------------
// Final: out = x @ W_base + b_base + a @ Wa_up[idx[b]] + ba_up[idx[b]]
// 1D grid 1024, XCD-chunked.  K=1024 base + K=64 adapter (1 step).
// ---------------------------------------------------------------------------
__global__ __launch_bounds__(THREADS) void final_kernel(
    const ushort_t* __restrict__ x, const ushort_t* __restrict__ WbT,
    const float* __restrict__ b_base, const ushort_t* __restrict__ a,
    const ushort_t* __restrict__ WauT, const float* __restrict__ ba_up,
    const int* __restrict__ idx, float* __restrict__ out) {
  __shared__ ushort_t As[128 * 64], Bs[128 * 64];
  int b = blockIdx.x;
  int work = (b & 7) * 128 + (b >> 3);   // 1024 % 8 == 0
  int m0 = (work >> 3) * 128;
  int n0 = (work & 7) * 128;
  int e = idx[m0 >> 11];
  int tid = threadIdx.x, wid = tid >> 6, lane = tid & 63;
  int wm = wid >> 1, wn = wid & 1;
  ACC_INIT(acc);
  gemm_kloop64<128, 128>(x, 1024, m0, WbT, 1024, n0, 1024, As, Bs, tid, wm,
                         wn, acc);
  gemm_kloop64<128, 128>(a, 64, m0, WauT + (size_t)e * 1024 * 64, 64, n0, 64,
                         As, Bs, tid, wm, wn, acc);
  int r = lane & 15, q = lane >> 4;
#pragma unroll
  for (int ni = 0; ni < 4; ++ni) {
    int col = n0 + wn * 64 + ni * 16 + r;
    float bias = b_base[col] + ba_up[e * 1024 + col];
#pragma unroll
    for (int mi = 0; mi < 4; ++mi) {
      int rowb = m0 + wm * 64 + mi * 16 + q * 4;
#pragma unroll
      for (int j = 0; j < 4; ++j)
        out[(size_t)(rowb + j) * 1024 + col] = acc[mi][ni][j] + bias;
    }
  }
}

// ---------------------------------------------------------------------------
// Host launcher
// ---------------------------------------------------------------------------
extern "C" void kernel_launch(void* const* d_in, const int* in_sizes, int n_in,
                              void* d_out, int out_size, void* d_ws,
                              size_t ws_size, hipStream_t stream) {
  const float* x       = (const float*)d_in[0];
  const float* W_base  = (const float*)d_in[1];
  const float* b_base  = (const float*)d_in[2];
  const float* Wd1     = (const float*)d_in[3];
  const float* bd1     = (const float*)d_in[4];
  const float* Wd2     = (const float*)d_in[5];
  const float* bd2     = (const float*)d_in[6];
  const float* Wa_down = (const float*)d_in[7];
  const float* ba_down = (const float*)d_in[8];
  const float* Wa_up   = (const float*)d_in[9];
  const float* ba_up   = (const float*)d_in[10];
  float* out = (float*)d_out;

  char* w = (char*)d_ws;
  size_t off = 0;
  auto alloc = [&](size_t bytes) {
    void* p = w + off;
    off += (bytes + 255) & ~(size_t)255;
    return p;
  };
  ushort_t* x_bf = (ushort_t*)alloc((size_t)16384 * 1024 * 2);
  ushort_t* Wd1T = (ushort_t*)alloc((size_t)8 * 256 * 1024 * 2);
  ushort_t* Wd2T = (ushort_t*)alloc((size_t)8 * 1024 * 256 * 2);
  ushort_t* WbT  = (ushort_t*)alloc((size_t)1024 * 1024 * 2);
  ushort_t* WadT = (ushort_t*)alloc((size_t)8 * 64 * 1024 * 2);
  ushort_t* WauT = (ushort_t*)alloc((size_t)8 * 1024 * 64 * 2);
  ushort_t* abuf = (ushort_t*)alloc((size_t)16384 * 64 * 2);
  float* losses  = (float*)alloc(64 * 4);
  int* idxb      = (int*)alloc(64);
  size_t hbytes = (size_t)8 * 16384 * 256 * 2;  // 67 MB
  ushort_t* h = (ws_size >= off + hbytes) ? (ushort_t*)alloc(hbytes)
                                          : (ushort_t*)d_out;  // out rewritten later

  // prologue: cast + all transposes (also zeroes losses)
  cast_x_kernel<<<2048, 256, 0, stream>>>((const float4*)x, (ushort4*)x_bf,
                                          16777216 / 4);
  transpose_all_kernel<<<6144, dim3(32, 8), 0, stream>>>(
      Wd1, Wd2, W_base, Wa_down, Wa_up, Wd1T, Wd2T, WbT, WadT, WauT, losses);

  // discriminators
  disc_h_kernel<<<2048, THREADS, 0, stream>>>(x_bf, Wd1T, bd1, h);
  disc_loss_kernel<<<8192, THREADS, 0, stream>>>(h, Wd2T, bd2, x_bf, losses);
  argmin_kernel<<<1, 64, 0, stream>>>(losses, idxb);

  // adapter + base
  adapter_down_kernel<<<64, THREADS, 0, stream>>>(x_bf, WadT, ba_down, idxb,
                                                  abuf);
  final_kernel<<<1024, THREADS, 0, stream>>>(x_bf, WbT, b_base, abuf,
                                             WauT, ba_up, idxb, out);
}

// Round 7
// 330.639 us; speedup vs baseline: 1.2412x; 1.1519x over previous
//
#include <hip/hip_runtime.h>

// ---------------------------------------------------------------------------
// Types
// ---------------------------------------------------------------------------
typedef __bf16 bf16x8 __attribute__((ext_vector_type(8)));
typedef float f32x4 __attribute__((ext_vector_type(4)));
typedef unsigned short ushort_t;

#define THREADS 256

__device__ __forceinline__ unsigned short f2bf(float f) {
  unsigned int u = __builtin_bit_cast(unsigned int, f);
  u += 0x7fffu + ((u >> 16) & 1u);   // RNE (no NaN in this data)
  return (unsigned short)(u >> 16);
}

__device__ __forceinline__ float bf2f(ushort_t u) {
  unsigned int v = ((unsigned int)u) << 16;
  return __builtin_bit_cast(float, v);
}

__device__ __forceinline__ void gload_lds16(const ushort_t* g, ushort_t* l) {
  __builtin_amdgcn_global_load_lds(
      (const __attribute__((address_space(1))) void*)g,
      (__attribute__((address_space(3))) void*)l, 16, 0, 0);
}

// ---------------------------------------------------------------------------
// cast x -> bf16
// ---------------------------------------------------------------------------
__global__ void cast_x_kernel(const float4* __restrict__ src,
                              ushort4* __restrict__ dst, int n4) {
  int stride = gridDim.x * blockDim.x;
  for (int i = blockIdx.x * blockDim.x + threadIdx.x; i < n4; i += stride) {
    float4 v = src[i];
    ushort4 o;
    o.x = f2bf(v.x); o.y = f2bf(v.y); o.z = f2bf(v.z); o.w = f2bf(v.w);
    dst[i] = o;
  }
}

// ---------------------------------------------------------------------------
// All weight transposes in ONE kernel (proven in round 6).  block (32,8);
// 6144 blocks; also zeroes losses[64] (block 0).
// ---------------------------------------------------------------------------
__global__ void transpose_all_kernel(
    const float* __restrict__ Wd1, const float* __restrict__ Wd2,
    const float* __restrict__ Wb, const float* __restrict__ Wad,
    const float* __restrict__ Wau, ushort_t* __restrict__ Wd1T,
    ushort_t* __restrict__ Wd2T, ushort_t* __restrict__ WbT,
    ushort_t* __restrict__ WadT, ushort_t* __restrict__ WauT,
    float* __restrict__ losses) {
  __shared__ float t[32][33];
  int b = blockIdx.x;
  int tx = threadIdx.x, ty = threadIdx.y;
  int ft = ty * 32 + tx;
  if (b == 0 && ft < 64) losses[ft] = 0.f;

  const float* src;
  ushort_t* dst;
  int R, C, z, cx, ry;
  if (b < 2048) {
    src = Wd1; dst = Wd1T; R = 1024; C = 256;
    z = b >> 8; int rem = b & 255; cx = rem & 7; ry = rem >> 3;
  } else if (b < 4096) {
    int bb = b - 2048;
    src = Wd2; dst = Wd2T; R = 256; C = 1024;
    z = bb >> 8; int rem = bb & 255; cx = rem & 31; ry = rem >> 5;
  } else if (b < 5120) {
    int bb = b - 4096;
    src = Wb; dst = WbT; R = 1024; C = 1024;
    z = 0; cx = bb & 31; ry = bb >> 5;
  } else if (b < 5632) {
    int bb = b - 5120;
    src = Wad; dst = WadT; R = 1024; C = 64;
    z = bb >> 6; int rem = bb & 63; cx = rem & 1; ry = rem >> 1;
  } else {
    int bb = b - 5632;
    src = Wau; dst = WauT; R = 64; C = 1024;
    z = bb >> 6; int rem = bb & 63; cx = rem & 31; ry = rem >> 5;
  }
  size_t zoff = (size_t)z * R * C;
  src += zoff; dst += zoff;
  int c0 = cx * 32, r0 = ry * 32;
#pragma unroll
  for (int i = 0; i < 4; ++i)
    t[ty + 8 * i][tx] = src[(size_t)(r0 + ty + 8 * i) * C + c0 + tx];
  __syncthreads();
#pragma unroll
  for (int i = 0; i < 4; ++i)
    dst[(size_t)(c0 + ty + 8 * i) * R + r0 + tx] = f2bf(t[tx][ty + 8 * i]);
}

// ---------------------------------------------------------------------------
// Swizzled staging (R4-proven, conflict-free).
// LDS tile [ROWS][32] bf16; slot s of row holds global k-chunk s ^ ((row>>1)&3).
// ---------------------------------------------------------------------------
__device__ __forceinline__ int sw(int row) { return (row >> 1) & 3; }

__device__ __forceinline__ bf16x8 frag_sw(const ushort_t* lds, int row, int q) {
  int slot = q ^ sw(row);
  return *(const bf16x8*)(lds + (row * 4 + slot) * 8);
}

#define ACC_ZERO(acc, MM, NN)                        \
  _Pragma("unroll") for (int _i = 0; _i < MM; ++_i)  \
  _Pragma("unroll") for (int _j = 0; _j < NN; ++_j)  \
      acc[_i][_j] = (f32x4){0.f, 0.f, 0.f, 0.f};

// ---------------------------------------------------------------------------
// R4-proven lean 2-phase GEMM: tile BM x BN, acc[4][4]/wave, BK=32,
// 256 threads, single-buffered, stage -> sync -> mma -> sync.
// ---------------------------------------------------------------------------
template <int BM, int BN>
__device__ __forceinline__ void stage_tiles(const ushort_t* __restrict__ A,
                                            size_t lda, int arow0,
                                            const ushort_t* __restrict__ BT,
                                            size_t ldb, int brow0, int k0,
                                            ushort_t* As, ushort_t* Bs,
                                            int tid) {
#pragma unroll
  for (int i = 0; i < BM / 64; ++i) {
    int c = tid + i * THREADS;
    int row = c >> 2, slot = c & 3;
    int g = slot ^ sw(row);
    gload_lds16(A + (size_t)(arow0 + row) * lda + k0 + g * 8, As + c * 8);
  }
#pragma unroll
  for (int i = 0; i < BN / 64; ++i) {
    int c = tid + i * THREADS;
    int row = c >> 2, slot = c & 3;
    int g = slot ^ sw(row);
    gload_lds16(BT + (size_t)(brow0 + row) * ldb + k0 + g * 8, Bs + c * 8);
  }
}

__device__ __forceinline__ void mma_step(const ushort_t* As, const ushort_t* Bs,
                                         int wm, int wn, int lane,
                                         f32x4 acc[4][4]) {
  int r = lane & 15, q = lane >> 4;
  bf16x8 a[4], b[4];
#pragma unroll
  for (int mi = 0; mi < 4; ++mi)
    a[mi] = frag_sw(As, wm * 64 + mi * 16 + r, q);
#pragma unroll
  for (int ni = 0; ni < 4; ++ni)
    b[ni] = frag_sw(Bs, wn * 64 + ni * 16 + r, q);
#pragma unroll
  for (int mi = 0; mi < 4; ++mi)
#pragma unroll
    for (int ni = 0; ni < 4; ++ni)
      acc[mi][ni] =
          __builtin_amdgcn_mfma_f32_16x16x32_bf16(a[mi], b[ni], acc[mi][ni], 0, 0, 0);
}

template <int BM, int BN>
__device__ __forceinline__ void gemm_kloop(const ushort_t* __restrict__ A,
                                           size_t lda, int arow0,
                                           const ushort_t* __restrict__ BT,
                                           size_t ldb, int brow0, int K,
                                           ushort_t* As, ushort_t* Bs, int tid,
                                           int wm, int wn, f32x4 acc[4][4]) {
  int lane = tid & 63;
  for (int k0 = 0; k0 < K; k0 += 32) {
    stage_tiles<BM, BN>(A, lda, arow0, BT, ldb, brow0, k0, As, Bs, tid);
    __syncthreads();
    mma_step(As, Bs, wm, wn, lane, acc);
    __syncthreads();
  }
}

#define ACC_INIT(acc)  \
  f32x4 acc[4][4];     \
  ACC_ZERO(acc, 4, 4)

// ---------------------------------------------------------------------------
// disc_h: h = relu(x @ Wd1_all + bd1_all), one GEMM M=16384, N=2048, K=1024.
// Output scattered into h[e][16384][256] (e = col>>8).  1D grid 2048,
// XCD-chunked (16 consecutive m-tiles per XCD, n fastest).
// ---------------------------------------------------------------------------
__global__ __launch_bounds__(THREADS) void disc_h_kernel(
    const ushort_t* __restrict__ x_bf, const ushort_t* __restrict__ Wd1T,
    const float* __restrict__ bd1, ushort_t* __restrict__ h) {
  __shared__ ushort_t As[128 * 32], Bs[128 * 32];
  int b = blockIdx.x;
  int work = (b & 7) * 256 + (b >> 3);   // bijective XCD chunk (2048 % 8 == 0)
  int m0 = (work >> 4) * 128;
  int n0 = (work & 15) * 128;
  int tid = threadIdx.x, wid = tid >> 6, lane = tid & 63;
  int wm = wid >> 1, wn = wid & 1;
  ACC_INIT(acc);
  gemm_kloop<128, 128>(x_bf, 1024, m0, Wd1T, 1024, n0, 1024, As, Bs, tid, wm,
                       wn, acc);
  int r = lane & 15, q = lane >> 4;
#pragma unroll
  for (int ni = 0; ni < 4; ++ni) {
    int col = n0 + wn * 64 + ni * 16 + r;
    float bias = bd1[col];
    int e = col >> 8, nn = col & 255;
    ushort_t* hp = h + (size_t)e * 16384 * 256 + nn;
#pragma unroll
    for (int mi = 0; mi < 4; ++mi) {
      int rowb = m0 + wm * 64 + mi * 16 + q * 4;
#pragma unroll
      for (int j = 0; j < 4; ++j) {
        float v = fmaxf(acc[mi][ni][j] + bias, 0.f);
        hp[(size_t)(rowb + j) * 256] = f2bf(v);
      }
    }
  }
}

// ---------------------------------------------------------------------------
// disc_loss: recon = h[e] @ Wd2[e] + bd2[e]; sum((recon-x)^2) -> losses.
// Tile 128x128, K=256.  1D grid 8192; expert e -> XCD e.
// ---------------------------------------------------------------------------
__global__ __launch_bounds__(THREADS) void disc_loss_kernel(
    const ushort_t* __restrict__ h, const ushort_t* __restrict__ Wd2T,
    const float* __restrict__ bd2, const ushort_t* __restrict__ x_bf,
    float* __restrict__ losses) {
  __shared__ ushort_t As[128 * 32], Bs[128 * 32];
  __shared__ float red[4];
  int b = blockIdx.x;
  int work = (b & 7) * 1024 + (b >> 3);  // 8192 % 8 == 0
  int e = work >> 10;                    // 1024 blocks per expert -> one XCD
  int m0 = ((work >> 3) & 127) * 128;
  int n0 = (work & 7) * 128;
  int tid = threadIdx.x, wid = tid >> 6, lane = tid & 63;
  int wm = wid >> 1, wn = wid & 1;
  int r = lane & 15, q = lane >> 4;
  const ushort_t* hA = h + (size_t)e * 16384 * 256;
  const ushort_t* W2 = Wd2T + (size_t)e * 1024 * 256;

  ACC_INIT(acc);
  gemm_kloop<128, 128>(hA, 256, m0, W2, 256, n0, 256, As, Bs, tid, wm, wn, acc);

  float s = 0.f;
#pragma unroll
  for (int ni = 0; ni < 4; ++ni) {
    int colg = n0 + wn * 64 + ni * 16 + r;
    float bias = bd2[e * 1024 + colg];
#pragma unroll
    for (int mi = 0; mi < 4; ++mi) {
      int rowg = m0 + wm * 64 + mi * 16 + q * 4;
#pragma unroll
      for (int j = 0; j < 4; ++j) {
        float v = acc[mi][ni][j] + bias -
                  bf2f(x_bf[(size_t)(rowg + j) * 1024 + colg]);
        s += v * v;
      }
    }
  }
#pragma unroll
  for (int off = 32; off > 0; off >>= 1) s += __shfl_down(s, off);
  if (lane == 0) red[wid] = s;
  __syncthreads();
  if (tid == 0) {
    float t = red[0] + red[1] + red[2] + red[3];
    atomicAdd(&losses[e * 8 + (m0 >> 11)], t);
  }
}

__global__ void argmin_kernel(const float* __restrict__ losses,
                              int* __restrict__ idx) {
  int b = threadIdx.x;
  if (b < 8) {
    float best = losses[b];
    int bi = 0;
    for (int e = 1; e < 8; ++e) {
      float v = losses[e * 8 + b];
      if (v < best) { best = v; bi = e; }
    }
    idx[b] = bi;
  }
}

// ---------------------------------------------------------------------------
// Adapter down: a = relu(x @ Wa_down[idx[b]] + ba_down[idx[b]]), bf16 out.
// Tile 256x64, K=1024.  grid 64.
// ---------------------------------------------------------------------------
__global__ __launch_bounds__(THREADS) void adapter_down_kernel(
    const ushort_t* __restrict__ x, const ushort_t* __restrict__ WadT,
    const float* __restrict__ ba_down, const int* __restrict__ idx,
    ushort_t* __restrict__ a) {
  __shared__ ushort_t As[256 * 32], Bs[64 * 32];
  int m0 = blockIdx.x * 256;
  int e = idx[m0 >> 11];
  int tid = threadIdx.x, wid = tid >> 6, lane = tid & 63;
  ACC_INIT(acc);
  gemm_kloop<256, 64>(x, 1024, m0, WadT + (size_t)e * 64 * 1024, 1024, 0, 1024,
                      As, Bs, tid, wid, 0, acc);
  int r = lane & 15, q = lane >> 4;
#pragma unroll
  for (int ni = 0; ni < 4; ++ni) {
    int col = ni * 16 + r;
    float bias = ba_down[e * 64 + col];
#pragma unroll
    for (int mi = 0; mi < 4; ++mi) {
      int rowb = m0 + wid * 64 + mi * 16 + q * 4;
#pragma unroll
      for (int j = 0; j < 4; ++j) {
        float v = acc[mi][ni][j] + bias;
        v = fmaxf(v, 0.f);
        a[(size_t)(rowb + j) * 64 + col] = f2bf(v);
      }
    }
  }
}

// ---------------------------------------------------------------------------
// Final: out = x @ W_base + b_base + a @ Wa_up[idx[b]] + ba_up[idx[b]]
// 1D grid 1024, XCD-chunked.
// ---------------------------------------------------------------------------
__global__ __launch_bounds__(THREADS) void final_kernel(
    const ushort_t* __restrict__ x, const ushort_t* __restrict__ WbT,
    const float* __restrict__ b_base, const ushort_t* __restrict__ a,
    const ushort_t* __restrict__ WauT, const float* __restrict__ ba_up,
    const int* __restrict__ idx, float* __restrict__ out) {
  __shared__ ushort_t As[128 * 32], Bs[128 * 32];
  int b = blockIdx.x;
  int work = (b & 7) * 128 + (b >> 3);   // 1024 % 8 == 0
  int m0 = (work >> 3) * 128;
  int n0 = (work & 7) * 128;
  int e = idx[m0 >> 11];
  int tid = threadIdx.x, wid = tid >> 6, lane = tid & 63;
  int wm = wid >> 1, wn = wid & 1;
  ACC_INIT(acc);
  gemm_kloop<128, 128>(x, 1024, m0, WbT, 1024, n0, 1024, As, Bs, tid, wm, wn, acc);
  gemm_kloop<128, 128>(a, 64, m0, WauT + (size_t)e * 1024 * 64, 64, n0, 64, As,
                       Bs, tid, wm, wn, acc);
  int r = lane & 15, q = lane >> 4;
#pragma unroll
  for (int ni = 0; ni < 4; ++ni) {
    int col = n0 + wn * 64 + ni * 16 + r;
    float bias = b_base[col] + ba_up[e * 1024 + col];
#pragma unroll
    for (int mi = 0; mi < 4; ++mi) {
      int rowb = m0 + wm * 64 + mi * 16 + q * 4;
#pragma unroll
      for (int j = 0; j < 4; ++j)
        out[(size_t)(rowb + j) * 1024 + col] = acc[mi][ni][j] + bias;
    }
  }
}

// ---------------------------------------------------------------------------
// Host launcher
// ---------------------------------------------------------------------------
extern "C" void kernel_launch(void* const* d_in, const int* in_sizes, int n_in,
                              void* d_out, int out_size, void* d_ws,
                              size_t ws_size, hipStream_t stream) {
  const float* x       = (const float*)d_in[0];
  const float* W_base  = (const float*)d_in[1];
  const float* b_base  = (const float*)d_in[2];
  const float* Wd1     = (const float*)d_in[3];
  const float* bd1     = (const float*)d_in[4];
  const float* Wd2     = (const float*)d_in[5];
  const float* bd2     = (const float*)d_in[6];
  const float* Wa_down = (const float*)d_in[7];
  const float* ba_down = (const float*)d_in[8];
  const float* Wa_up   = (const float*)d_in[9];
  const float* ba_up   = (const float*)d_in[10];
  float* out = (float*)d_out;

  char* w = (char*)d_ws;
  size_t off = 0;
  auto alloc = [&](size_t bytes) {
    void* p = w + off;
    off += (bytes + 255) & ~(size_t)255;
    return p;
  };
  ushort_t* x_bf = (ushort_t*)alloc((size_t)16384 * 1024 * 2);
  ushort_t* Wd1T = (ushort_t*)alloc((size_t)8 * 256 * 1024 * 2);
  ushort_t* Wd2T = (ushort_t*)alloc((size_t)8 * 1024 * 256 * 2);
  ushort_t* WbT  = (ushort_t*)alloc((size_t)1024 * 1024 * 2);
  ushort_t* WadT = (ushort_t*)alloc((size_t)8 * 64 * 1024 * 2);
  ushort_t* WauT = (ushort_t*)alloc((size_t)8 * 1024 * 64 * 2);
  ushort_t* abuf = (ushort_t*)alloc((size_t)16384 * 64 * 2);
  float* losses  = (float*)alloc(64 * 4);
  int* idxb      = (int*)alloc(64);
  size_t hbytes = (size_t)8 * 16384 * 256 * 2;  // 67 MB
  ushort_t* h = (ws_size >= off + hbytes) ? (ushort_t*)alloc(hbytes)
                                          : (ushort_t*)d_out;  // out rewritten later

  // prologue: cast + all transposes (also zeroes losses)
  cast_x_kernel<<<2048, 256, 0, stream>>>((const float4*)x, (ushort4*)x_bf,
                                          16777216 / 4);
  transpose_all_kernel<<<6144, dim3(32, 8), 0, stream>>>(
      Wd1, Wd2, W_base, Wa_down, Wa_up, Wd1T, Wd2T, WbT, WadT, WauT, losses);

  // discriminators
  disc_h_kernel<<<2048, THREADS, 0, stream>>>(x_bf, Wd1T, bd1, h);
  disc_loss_kernel<<<8192, THREADS, 0, stream>>>(h, Wd2T, bd2, x_bf, losses);
  argmin_kernel<<<1, 64, 0, stream>>>(losses, idxb);

  // adapter + base
  adapter_down_kernel<<<64, THREADS, 0, stream>>>(x_bf, WadT, ba_down, idxb,
                                                  abuf);
  final_kernel<<<1024, THREADS, 0, stream>>>(x_bf, WbT, b_base, abuf,
                                             WauT, ba_up, idxb, out);
}